// Round 6
// baseline (309.963 us; speedup 1.0000x reference)
//
#include <hip/hip_runtime.h>

#define S_LEN 2048
#define HD 64
#define KVB 64
#define NT (S_LEN / KVB)   // 32 kv tiles

typedef float f32x4  __attribute__((ext_vector_type(4)));
typedef float f32x16 __attribute__((ext_vector_type(16)));
typedef short bf16x8 __attribute__((ext_vector_type(8)));
typedef int   i32x4  __attribute__((ext_vector_type(4)));

#define SQ_SCALE 0.18033688011112042f   // 0.125 * log2(e)
#define MASK_B  (-1442695.040888963f)   // -1e6 * log2(e)
#define THR 10.0f

static __device__ __forceinline__ int cvt_pk(float lo, float hi) {
  int r;
  asm("v_cvt_pk_bf16_f32 %0, %1, %2" : "=v"(r) : "v"(lo), "v"(hi));
  return r;
}
static __device__ __forceinline__ float exp2v(float x) {
  float r;
  asm("v_exp_f32 %0, %1" : "=v"(r) : "v"(x));
  return r;
}
static __device__ __forceinline__ void swap32(int &a, int &b) {
  asm("v_permlane32_swap_b32 %0, %1" : "+v"(a), "+v"(b));
}

__global__ __launch_bounds__(512, 4)
void attn_fwd(const float* __restrict__ Qg, const float* __restrict__ Kg,
              const float* __restrict__ Vg, const int* __restrict__ Mg,
              float* __restrict__ Og) {
  // K tile: [64 keys][72 d] bf16; V^T tile: [64 d][72 keys] bf16; mask bias f32
  __shared__ __align__(16) short Klds[2][64 * 72];
  __shared__ __align__(16) short Vtld[2][64 * 72];
  __shared__ __align__(16) float MB[2][64];

  const int t    = threadIdx.x;
  const int lane = t & 63;
  const int wid  = t >> 6;      // 0..7
  const int c    = lane & 31;   // q column (and d-row for V^T A-frag)
  const int hi   = lane >> 5;   // lane half

  // XCD-aware swizzle (bijective: 512 = 8 XCDs x 64): the 8 q-blocks of each
  // bh land on one XCD -> K/V panel read once per XCD L2.
  const int bid  = (int)blockIdx.x;
  const int swz  = (bid & 7) * 64 + (bid >> 3);
  const int bh   = swz >> 3;                // 0..63
  const int qblk = (swz & 7) * 256;         // 256 q rows per block
  const int b    = bh >> 4;                 // batch (H=16)
  const size_t base = (size_t)bh * S_LEN * HD;
  const int qbase = qblk + wid * 32;        // this wave's 32 q rows

  // ---- Q fragment (B-operand of QK^T): lane holds Q[qbase+c][16s+8hi .. +7]
  bf16x8 qf[4];
#pragma unroll
  for (int s = 0; s < 4; ++s) {
    const float* qp = Qg + base + (size_t)(qbase + c) * HD + 16*s + 8*hi;
    float4 x0 = *(const float4*)qp;
    float4 x1 = *(const float4*)(qp + 4);
    i32x4 w;
    w[0] = cvt_pk(x0.x*SQ_SCALE, x0.y*SQ_SCALE);
    w[1] = cvt_pk(x0.z*SQ_SCALE, x0.w*SQ_SCALE);
    w[2] = cvt_pk(x1.x*SQ_SCALE, x1.y*SQ_SCALE);
    w[3] = cvt_pk(x1.z*SQ_SCALE, x1.w*SQ_SCALE);
    qf[s] = __builtin_bit_cast(bf16x8, w);
  }

  // ---- staging roles (512 threads, one 64x64 tile each of K and V)
  // K: thread -> (key = t>>3, d-block dg). dg is XOR-permuted within each
  // 8-lane group: LDS content identical, ds_write start banks spread,
  // global coalescing preserved (permutation within a 2KB segment).
  const int kkey = t >> 3;
  const int kdg  = (t & 7) ^ ((t >> 3) & 7);
  // V: thread -> (column d = t&63, 8 keys starting at 8*(t>>6))
  const int vd   = t & 63;
  const int vkg  = t >> 6;

  const float* kptr = Kg + base + (size_t)kkey * HD + 8*kdg;
  const float* vptr = Vg + base + (size_t)(8*vkg) * HD + vd;
  const int*   mptr = Mg + (size_t)b * S_LEN + t;   // valid for t<64

  float kr[8], vr[8]; float mbias = 0.f;

  auto LOADN = [&]() {   // load next tile, auto-advance pointers
    *(float4*)&kr[0] = *(const float4*)kptr;
    *(float4*)&kr[4] = *(const float4*)(kptr + 4);
    kptr += KVB * HD;
#pragma unroll
    for (int j = 0; j < 8; ++j) vr[j] = vptr[j * HD];
    vptr += KVB * HD;
    if (t < 64) {
      mbias = (*mptr) ? 0.f : MASK_B;
      mptr += KVB;
    }
  };
  auto STORET = [&](int bf) {
    i32x4 kw;
    kw[0] = cvt_pk(kr[0], kr[1]); kw[1] = cvt_pk(kr[2], kr[3]);
    kw[2] = cvt_pk(kr[4], kr[5]); kw[3] = cvt_pk(kr[6], kr[7]);
    *(i32x4*)&Klds[bf][kkey*72 + 8*kdg] = kw;
    i32x4 vw;
    vw[0] = cvt_pk(vr[0], vr[1]); vw[1] = cvt_pk(vr[2], vr[3]);
    vw[2] = cvt_pk(vr[4], vr[5]); vw[3] = cvt_pk(vr[6], vr[7]);
    *(i32x4*)&Vtld[bf][vd*72 + 8*vkg] = vw;
    if (t < 64) MB[bf][t] = mbias;
  };

  f32x16 acc0 = {};  // O^T rows d=0..31
  f32x16 acc1 = {};  // O^T rows d=32..63
  float mrun = -1e30f;
  float lrun = 0.f;  // per-lane partial row-sum (this hi-half's keys);
                     // merged across hi at epilogue (rescale is hi-uniform).

  auto COMPUTE = [&](int cur) {
    // ---- S^T = K · Q^T (rows=keys, cols=q); two 32-key groups
    f32x16 S0 = {}, S1 = {};
    __builtin_amdgcn_s_setprio(1);
#pragma unroll
    for (int s = 0; s < 4; ++s) {
      bf16x8 kf0 = *(const bf16x8*)&Klds[cur][(c     )*72 + 16*s + 8*hi];
      bf16x8 kf1 = *(const bf16x8*)&Klds[cur][(c + 32)*72 + 16*s + 8*hi];
      S0 = __builtin_amdgcn_mfma_f32_32x32x16_bf16(kf0, qf[s], S0, 0, 0, 0);
      S1 = __builtin_amdgcn_mfma_f32_32x32x16_bf16(kf1, qf[s], S1, 0, 0, 0);
    }
    __builtin_amdgcn_s_setprio(0);

    f32x4 b4[8];
#pragma unroll
    for (int m = 0; m < 8; ++m)
      b4[m] = *(const f32x4*)&MB[cur][8*m + 4*hi];

    // sb0[r]: key (r&3)+8*(r>>2)+4*hi ; sb1[r]: that +32 ; q=c
    float sb0[16], sb1[16];
#pragma unroll
    for (int r = 0; r < 16; ++r) sb0[r] = S0[r] + b4[r >> 2][r & 3];
#pragma unroll
    for (int r = 0; r < 16; ++r) sb1[r] = S1[r] + b4[4 + (r >> 2)][r & 3];

    // row max over this tile's 64 keys (fmax triples -> v_max3)
    float mx[8];
#pragma unroll
    for (int r = 0; r < 8; ++r)
      mx[r] = fmaxf(fmaxf(sb0[r], sb0[r+8]), fmaxf(sb1[r], sb1[r+8]));
#pragma unroll
    for (int r = 0; r < 4; ++r) mx[r] = fmaxf(mx[r], mx[r+4]);
    float tmax = fmaxf(fmaxf(mx[0], mx[1]), fmaxf(mx[2], mx[3]));
    tmax = fmaxf(tmax, __shfl_xor(tmax, 32, 64));

    // defer-max: rescale only when the running max grows by > THR
    if (!__all(tmax <= mrun + THR)) {
      float mnew = fmaxf(mrun, tmax);
      float al = exp2v(mrun - mnew);
      acc0 *= al; acc1 *= al;
      lrun *= al; mrun = mnew;
    }

    // p = exp2(logit2 - m)
    float p0[16], p1[16];
#pragma unroll
    for (int r = 0; r < 16; ++r) p0[r] = exp2v(sb0[r] - mrun);
#pragma unroll
    for (int r = 0; r < 16; ++r) p1[r] = exp2v(sb1[r] - mrun);

    // hoist V fragments: A[d][k], k-step ks covers keys 16ks..16ks+15
    bf16x8 vA[4], vB[4];
#pragma unroll
    for (int ks = 0; ks < 4; ++ks) {
      vA[ks] = *(const bf16x8*)&Vtld[cur][(c     )*72 + 16*ks + 8*hi];
      vB[ks] = *(const bf16x8*)&Vtld[cur][(c + 32)*72 + 16*ks + 8*hi];
    }

    // pack P to bf16 B-fragments: per 32-key group (proven recipe)
    int w0[8], w1[8];
#pragma unroll
    for (int m = 0; m < 8; ++m) w0[m] = cvt_pk(p0[2*m], p0[2*m+1]);
#pragma unroll
    for (int m = 0; m < 8; ++m) w1[m] = cvt_pk(p1[2*m], p1[2*m+1]);
    swap32(w0[0], w0[2]); swap32(w0[1], w0[3]);
    swap32(w0[4], w0[6]); swap32(w0[5], w0[7]);
    swap32(w1[0], w1[2]); swap32(w1[1], w1[3]);
    swap32(w1[4], w1[6]); swap32(w1[5], w1[7]);
    i32x4 q0 = {w0[0], w0[1], w0[2], w0[3]};   // keys  0..15
    i32x4 q1 = {w0[4], w0[5], w0[6], w0[7]};   // keys 16..31
    i32x4 q2 = {w1[0], w1[1], w1[2], w1[3]};   // keys 32..47
    i32x4 q3 = {w1[4], w1[5], w1[6], w1[7]};   // keys 48..63
    bf16x8 pb0 = __builtin_bit_cast(bf16x8, q0);
    bf16x8 pb1 = __builtin_bit_cast(bf16x8, q1);
    bf16x8 pb2 = __builtin_bit_cast(bf16x8, q2);
    bf16x8 pb3 = __builtin_bit_cast(bf16x8, q3);

    // ---- O^T += V^T · P^T
    __builtin_amdgcn_s_setprio(1);
    acc0 = __builtin_amdgcn_mfma_f32_32x32x16_bf16(vA[0], pb0, acc0, 0, 0, 0);
    acc1 = __builtin_amdgcn_mfma_f32_32x32x16_bf16(vB[0], pb0, acc1, 0, 0, 0);
    acc0 = __builtin_amdgcn_mfma_f32_32x32x16_bf16(vA[1], pb1, acc0, 0, 0, 0);
    acc1 = __builtin_amdgcn_mfma_f32_32x32x16_bf16(vB[1], pb1, acc1, 0, 0, 0);
    acc0 = __builtin_amdgcn_mfma_f32_32x32x16_bf16(vA[2], pb2, acc0, 0, 0, 0);
    acc1 = __builtin_amdgcn_mfma_f32_32x32x16_bf16(vB[2], pb2, acc1, 0, 0, 0);
    acc0 = __builtin_amdgcn_mfma_f32_32x32x16_bf16(vA[3], pb3, acc0, 0, 0, 0);
    acc1 = __builtin_amdgcn_mfma_f32_32x32x16_bf16(vB[3], pb3, acc1, 0, 0, 0);
    __builtin_amdgcn_s_setprio(0);

    // per-lane partial row-sum (no per-tile shfl)
    float s0 = 0.f, s1 = 0.f;
#pragma unroll
    for (int r = 0; r < 8; ++r) s0 += p0[r] + p0[r+8];
#pragma unroll
    for (int r = 0; r < 8; ++r) s1 += p1[r] + p1[r+8];
    lrun += s0 + s1;
  };

  // ---- prologue
  LOADN(); STORET(0);
  LOADN();
  __syncthreads();

  for (int it = 0; it < NT; ++it) {
    if (it + 1 < NT) STORET((it + 1) & 1);
    if (it + 2 < NT) LOADN();
    COMPUTE(it & 1);
    __syncthreads();
  }

  // ---- epilogue: merge partial l across hi halves; normalize; store fp32
  float lfull = lrun + __shfl_xor(lrun, 32, 64);
  const float linv = 1.0f / lfull;
  float* op = Og + base + (size_t)(qbase + c) * HD + 4*hi;
#pragma unroll
  for (int m = 0; m < 4; ++m) {
    f32x4 o0, o1;
#pragma unroll
    for (int j = 0; j < 4; ++j) {
      o0[j] = acc0[4*m + j] * linv;
      o1[j] = acc1[4*m + j] * linv;
    }
    *(f32x4*)(op + 8*m)      = o0;   // d = 8m+4hi .. +3
    *(f32x4*)(op + 32 + 8*m) = o1;   // d = 32+8m+4hi .. +3
  }
}

extern "C" void kernel_launch(void* const* d_in, const int* in_sizes, int n_in,
                              void* d_out, int out_size, void* d_ws, size_t ws_size,
                              hipStream_t stream) {
    const float* Q = (const float*)d_in[0];
    const float* K = (const float*)d_in[1];
    const float* V = (const float*)d_in[2];
    const int*   M = (const int*)d_in[3];
    float* O = (float*)d_out;
    dim3 grid(512), block(512);
    hipLaunchKernelGGL(attn_fwd, grid, block, 0, stream, Q, K, V, M, O);
}

// Round 7
// 100.062 us; speedup vs baseline: 3.0977x; 3.0977x over previous
//
#include <hip/hip_runtime.h>

#define S_LEN 2048
#define HD 64
#define KVB 64
#define NT (S_LEN / KVB)   // 32 kv tiles

typedef float f32x4  __attribute__((ext_vector_type(4)));
typedef float f32x16 __attribute__((ext_vector_type(16)));
typedef short bf16x8 __attribute__((ext_vector_type(8)));
typedef int   i32x4  __attribute__((ext_vector_type(4)));

#define SQ_SCALE 0.18033688011112042f   // 0.125 * log2(e)
#define MASK_B  (-1442695.040888963f)   // -1e6 * log2(e)
#define THR 10.0f

static __device__ __forceinline__ int cvt_pk(float lo, float hi) {
  int r;
  asm("v_cvt_pk_bf16_f32 %0, %1, %2" : "=v"(r) : "v"(lo), "v"(hi));
  return r;
}
static __device__ __forceinline__ float exp2v(float x) {
  float r;
  asm("v_exp_f32 %0, %1" : "=v"(r) : "v"(x));
  return r;
}
static __device__ __forceinline__ void swap32(int &a, int &b) {
  asm("v_permlane32_swap_b32 %0, %1" : "+v"(a), "+v"(b));
}

__global__ __launch_bounds__(512, 4)
void attn_fwd(const float* __restrict__ Qg, const float* __restrict__ Kg,
              const float* __restrict__ Vg, const int* __restrict__ Mg,
              float* __restrict__ Og) {
  // K tile: [64 keys][72 d] bf16; V^T tile: [64 d][72 keys] bf16; mask bias f32
  // (stride-72 + XOR'd K staging measured conflict-free in round 6)
  __shared__ __align__(16) short Klds[2][64 * 72];
  __shared__ __align__(16) short Vtld[2][64 * 72];
  __shared__ __align__(16) float MB[2][64];

  const int t    = threadIdx.x;
  const int lane = t & 63;
  const int wid  = t >> 6;      // 0..7
  const int c    = lane & 31;   // q column (and d-row for V^T A-frag)
  const int hi   = lane >> 5;   // lane half

  // XCD-aware swizzle (bijective: 512 = 8 XCDs x 64): the 8 q-blocks of each
  // bh land on one XCD -> K/V panel read once per XCD L2.
  const int bid  = (int)blockIdx.x;
  const int swz  = (bid & 7) * 64 + (bid >> 3);
  const int bh   = swz >> 3;                // 0..63
  const int qblk = (swz & 7) * 256;         // 256 q rows per block
  const int b    = bh >> 4;                 // batch (H=16)
  const size_t base = (size_t)bh * S_LEN * HD;
  const int qbase = qblk + wid * 32;        // this wave's 32 q rows

  // ---- Q fragment (B-operand of QK^T): lane holds Q[qbase+c][16s+8hi .. +7]
  bf16x8 qf[4];
#pragma unroll
  for (int s = 0; s < 4; ++s) {
    const float* qp = Qg + base + (size_t)(qbase + c) * HD + 16*s + 8*hi;
    float4 x0 = *(const float4*)qp;
    float4 x1 = *(const float4*)(qp + 4);
    i32x4 w;
    w[0] = cvt_pk(x0.x*SQ_SCALE, x0.y*SQ_SCALE);
    w[1] = cvt_pk(x0.z*SQ_SCALE, x0.w*SQ_SCALE);
    w[2] = cvt_pk(x1.x*SQ_SCALE, x1.y*SQ_SCALE);
    w[3] = cvt_pk(x1.z*SQ_SCALE, x1.w*SQ_SCALE);
    qf[s] = __builtin_bit_cast(bf16x8, w);
  }

  // ---- staging roles (512 threads stage one 64x64 K tile + V tile)
  // K: thread -> (key = t>>3, d-block dg XOR-permuted within 8-lane group:
  // LDS content identical, write banks spread, global coalescing kept).
  const int kkey = t >> 3;
  const int kdg  = (t & 7) ^ ((t >> 3) & 7);
  // V: thread -> (column d = t&63, 8 keys starting at 8*(t>>6))
  const int vd   = t & 63;
  const int vkg  = t >> 6;

  const float* kptr = Kg + base + (size_t)kkey * HD + 8*kdg;
  const float* vptr = Vg + base + (size_t)(8*vkg) * HD + vd;
  const int*   mptr = Mg + (size_t)b * S_LEN + t;   // valid for t<64

  float kr[8], vr[8]; float mbias = 0.f;

  auto LOADN = [&]() {   // load next tile, auto-advance pointers
    *(float4*)&kr[0] = *(const float4*)kptr;
    *(float4*)&kr[4] = *(const float4*)(kptr + 4);
    kptr += KVB * HD;
#pragma unroll
    for (int j = 0; j < 8; ++j) vr[j] = vptr[j * HD];
    vptr += KVB * HD;
    if (t < 64) {
      mbias = (*mptr) ? 0.f : MASK_B;
      mptr += KVB;
    }
  };
  auto STORET = [&](int bf) {
    i32x4 kw;
    kw[0] = cvt_pk(kr[0], kr[1]); kw[1] = cvt_pk(kr[2], kr[3]);
    kw[2] = cvt_pk(kr[4], kr[5]); kw[3] = cvt_pk(kr[6], kr[7]);
    *(i32x4*)&Klds[bf][kkey*72 + 8*kdg] = kw;
    i32x4 vw;
    vw[0] = cvt_pk(vr[0], vr[1]); vw[1] = cvt_pk(vr[2], vr[3]);
    vw[2] = cvt_pk(vr[4], vr[5]); vw[3] = cvt_pk(vr[6], vr[7]);
    *(i32x4*)&Vtld[bf][vd*72 + 8*vkg] = vw;
    if (t < 64) MB[bf][t] = mbias;
  };

  f32x16 acc0 = {};  // O^T rows d=0..31
  f32x16 acc1 = {};  // O^T rows d=32..63
  float mrun = -1e30f;
  float lrun = 0.f;  // per-lane partial row-sum (this hi-half's keys);
                     // merged across hi at epilogue (rescale is hi-uniform).

  // One 32-key group = round-5's proven COMPUTE body; state scoped inside
  // so peak live registers stay at the round-5 level (no spills).
  auto GROUP = [&](int cur, int grp) {
    const int kc = 32 * grp;
    // ---- S^T = K · Q^T  (rows = keys kc..kc+31, cols = q)
    f32x16 S = {};
    __builtin_amdgcn_s_setprio(1);
#pragma unroll
    for (int s = 0; s < 4; ++s) {
      bf16x8 kf = *(const bf16x8*)&Klds[cur][(kc + c)*72 + 16*s + 8*hi];
      S = __builtin_amdgcn_mfma_f32_32x32x16_bf16(kf, qf[s], S, 0, 0, 0);
    }
    __builtin_amdgcn_s_setprio(0);

    f32x4 b4[4];
#pragma unroll
    for (int m = 0; m < 4; ++m)
      b4[m] = *(const f32x4*)&MB[cur][kc + 8*m + 4*hi];

    // sb[r]: logit2 for key kc + (r&3)+8*(r>>2)+4*hi, q=c
    float sb[16];
#pragma unroll
    for (int r = 0; r < 16; ++r)
      sb[r] = S[r] + b4[r >> 2][r & 3];

    // row max over this group's 32 keys
    float mx[8];
#pragma unroll
    for (int r = 0; r < 8; ++r) mx[r] = fmaxf(sb[r], sb[r+8]);
#pragma unroll
    for (int r = 0; r < 4; ++r) mx[r] = fmaxf(mx[r], mx[r+4]);
    float tmax = fmaxf(fmaxf(mx[0], mx[1]), fmaxf(mx[2], mx[3]));
    tmax = fmaxf(tmax, __shfl_xor(tmax, 32, 64));

    // defer-max: rescale only when the running max grows by > THR
    if (!__all(tmax <= mrun + THR)) {
      float mnew = fmaxf(mrun, tmax);
      float al = exp2v(mrun - mnew);
      acc0 *= al; acc1 *= al;
      lrun *= al; mrun = mnew;
    }

    // p = exp2(logit2 - m)
    float p0[8], p1[8];
#pragma unroll
    for (int r = 0; r < 8; ++r) p0[r] = exp2v(sb[r] - mrun);
#pragma unroll
    for (int r = 0; r < 8; ++r) p1[r] = exp2v(sb[8 + r] - mrun);

    // pack P to bf16 B-fragments (proven permlane recipe)
    int w0 = cvt_pk(p0[0], p0[1]), w1 = cvt_pk(p0[2], p0[3]);
    int w2 = cvt_pk(p0[4], p0[5]), w3 = cvt_pk(p0[6], p0[7]);
    swap32(w0, w2); swap32(w1, w3);
    i32x4 pq0 = {w0, w1, w2, w3};
    bf16x8 pb0 = __builtin_bit_cast(bf16x8, pq0);   // keys kc..kc+15
    int w4 = cvt_pk(p1[0], p1[1]), w5 = cvt_pk(p1[2], p1[3]);
    int w6 = cvt_pk(p1[4], p1[5]), w7 = cvt_pk(p1[6], p1[7]);
    swap32(w4, w6); swap32(w5, w7);
    i32x4 pq1 = {w4, w5, w6, w7};
    bf16x8 pb1 = __builtin_bit_cast(bf16x8, pq1);   // keys kc+16..kc+31

    // V fragments just-in-time (16 regs only)
    bf16x8 vA0 = *(const bf16x8*)&Vtld[cur][(c     )*72 + kc      + 8*hi];
    bf16x8 vA1 = *(const bf16x8*)&Vtld[cur][(c     )*72 + kc + 16 + 8*hi];
    bf16x8 vB0 = *(const bf16x8*)&Vtld[cur][(c + 32)*72 + kc      + 8*hi];
    bf16x8 vB1 = *(const bf16x8*)&Vtld[cur][(c + 32)*72 + kc + 16 + 8*hi];

    // ---- O^T += V^T · P^T
    __builtin_amdgcn_s_setprio(1);
    acc0 = __builtin_amdgcn_mfma_f32_32x32x16_bf16(vA0, pb0, acc0, 0, 0, 0);
    acc1 = __builtin_amdgcn_mfma_f32_32x32x16_bf16(vB0, pb0, acc1, 0, 0, 0);
    acc0 = __builtin_amdgcn_mfma_f32_32x32x16_bf16(vA1, pb1, acc0, 0, 0, 0);
    acc1 = __builtin_amdgcn_mfma_f32_32x32x16_bf16(vB1, pb1, acc1, 0, 0, 0);
    __builtin_amdgcn_s_setprio(0);

    // per-lane partial row-sum (no per-tile shfl)
    float s0 = ((p0[0]+p0[1]) + (p0[2]+p0[3])) + ((p0[4]+p0[5]) + (p0[6]+p0[7]));
    float s1 = ((p1[0]+p1[1]) + (p1[2]+p1[3])) + ((p1[4]+p1[5]) + (p1[6]+p1[7]));
    lrun += s0 + s1;
  };

  // ---- prologue
  LOADN(); STORET(0);
  LOADN();
  __syncthreads();

  for (int it = 0; it < NT; ++it) {
    if (it + 1 < NT) STORET((it + 1) & 1);
    if (it + 2 < NT) LOADN();
    const int cur = it & 1;
    GROUP(cur, 0);
    GROUP(cur, 1);
    __syncthreads();
  }

  // ---- epilogue: merge partial l across hi halves; normalize; store fp32
  float lfull = lrun + __shfl_xor(lrun, 32, 64);
  const float linv = 1.0f / lfull;
  float* op = Og + base + (size_t)(qbase + c) * HD + 4*hi;
#pragma unroll
  for (int m = 0; m < 4; ++m) {
    f32x4 o0, o1;
#pragma unroll
    for (int j = 0; j < 4; ++j) {
      o0[j] = acc0[4*m + j] * linv;
      o1[j] = acc1[4*m + j] * linv;
    }
    *(f32x4*)(op + 8*m)      = o0;   // d = 8m+4hi .. +3
    *(f32x4*)(op + 32 + 8*m) = o1;   // d = 32+8m+4hi .. +3
  }
}

extern "C" void kernel_launch(void* const* d_in, const int* in_sizes, int n_in,
                              void* d_out, int out_size, void* d_ws, size_t ws_size,
                              hipStream_t stream) {
    const float* Q = (const float*)d_in[0];
    const float* K = (const float*)d_in[1];
    const float* V = (const float*)d_in[2];
    const int*   M = (const int*)d_in[3];
    float* O = (float*)d_out;
    dim3 grid(512), block(512);
    hipLaunchKernelGGL(attn_fwd, grid, block, 0, stream, Q, K, V, M, O);
}

// Round 8
// 76.869 us; speedup vs baseline: 4.0324x; 1.3017x over previous
//
#include <hip/hip_runtime.h>

#define S_LEN 2048
#define HD 64
#define KVB 64

typedef float f32x4  __attribute__((ext_vector_type(4)));
typedef float f32x16 __attribute__((ext_vector_type(16)));
typedef short bf16x8 __attribute__((ext_vector_type(8)));
typedef int   i32x4  __attribute__((ext_vector_type(4)));

#define SQ_SCALE 0.18033688011112042f   // 0.125 * log2(e)
#define MASK_B  (-1442695.040888963f)   // -1e6 * log2(e)
#define THR 10.0f

static __device__ __forceinline__ int cvt_pk(float lo, float hi) {
  int r;
  asm("v_cvt_pk_bf16_f32 %0, %1, %2" : "=v"(r) : "v"(lo), "v"(hi));
  return r;
}
static __device__ __forceinline__ float exp2v(float x) {
  float r;
  asm("v_exp_f32 %0, %1" : "=v"(r) : "v"(x));
  return r;
}
static __device__ __forceinline__ void swap32(int &a, int &b) {
  asm("v_permlane32_swap_b32 %0, %1" : "+v"(a), "+v"(b));
}

// ---- kernel 1: per-batch compaction of unmasked key indices (order kept).
// idxA[b][pos] = key for pos < cnt; pad region [cnt, pad) gets idx 0 with
// bias MASK_B so the attention kernel's existing bias path nulls it exactly.
__global__ __launch_bounds__(256)
void build_idx(const int* __restrict__ Mg, int* __restrict__ idxA,
               float* __restrict__ biasA, int* __restrict__ cntA) {
  const int b    = threadIdx.x >> 6;   // one wave per batch
  const int lane = threadIdx.x & 63;
  const int* m   = Mg + (size_t)b * S_LEN;
  int*   idx  = idxA  + (size_t)b * S_LEN;
  float* bias = biasA + (size_t)b * S_LEN;

  int offset = 0;
  for (int kb = 0; kb < S_LEN; kb += 64) {
    int live = (m[kb + lane] != 0);
    unsigned long long bal = __ballot(live);
    unsigned long long lt  = (1ull << lane) - 1ull;
    int pos = offset + (int)__popcll(bal & lt);
    if (live) idx[pos] = kb + lane;
    offset += (int)__popcll(bal);
  }
  const int cnt = offset;
  for (int j = lane; j < S_LEN; j += 64) {
    bias[j] = (j < cnt) ? 0.f : MASK_B;
    if (j >= cnt) idx[j] = 0;
  }
  if (lane == 0) cntA[b] = (cnt + 63) & ~63;   // padded to tile multiple
}

// ---- kernel 2: flash attention over gathered (unmasked) keys only.
__global__ __launch_bounds__(512, 4)
void attn_fwd(const float* __restrict__ Qg, const float* __restrict__ Kg,
              const float* __restrict__ Vg,
              const int* __restrict__ idxA, const float* __restrict__ biasA,
              const int* __restrict__ cntA, float* __restrict__ Og) {
  // K tile: [64 keys][72 d] bf16; V^T tile: [64 d][72 keys] bf16; bias f32
  // (stride-72 + XOR'd K staging measured conflict-free in round 6/7)
  __shared__ __align__(16) short Klds[2][64 * 72];
  __shared__ __align__(16) short Vtld[2][64 * 72];
  __shared__ __align__(16) float MB[2][64];

  const int t    = threadIdx.x;
  const int lane = t & 63;
  const int wid  = t >> 6;      // 0..7
  const int c    = lane & 31;   // q column (and d-row for V^T A-frag)
  const int hi   = lane >> 5;   // lane half

  // XCD-aware swizzle (bijective: 512 = 8 XCDs x 64)
  const int bid  = (int)blockIdx.x;
  const int swz  = (bid & 7) * 64 + (bid >> 3);
  const int bh   = swz >> 3;                // 0..63
  const int qblk = (swz & 7) * 256;         // 256 q rows per block
  const int b    = bh >> 4;                 // batch (H=16)
  const size_t base = (size_t)bh * S_LEN * HD;
  const int qbase = qblk + wid * 32;        // this wave's 32 q rows

  const int*   idx  = idxA  + (size_t)b * S_LEN;
  const float* bias = biasA + (size_t)b * S_LEN;
  const int NTd = cntA[b] >> 6;             // live tiles (>=1 in practice)

  // ---- Q fragment (B-operand of QK^T): lane holds Q[qbase+c][16s+8hi .. +7]
  bf16x8 qf[4];
#pragma unroll
  for (int s = 0; s < 4; ++s) {
    const float* qp = Qg + base + (size_t)(qbase + c) * HD + 16*s + 8*hi;
    float4 x0 = *(const float4*)qp;
    float4 x1 = *(const float4*)(qp + 4);
    i32x4 w;
    w[0] = cvt_pk(x0.x*SQ_SCALE, x0.y*SQ_SCALE);
    w[1] = cvt_pk(x0.z*SQ_SCALE, x0.w*SQ_SCALE);
    w[2] = cvt_pk(x1.x*SQ_SCALE, x1.y*SQ_SCALE);
    w[3] = cvt_pk(x1.z*SQ_SCALE, x1.w*SQ_SCALE);
    qf[s] = __builtin_bit_cast(bf16x8, w);
  }

  // ---- staging roles (512 threads stage one 64-key K tile + V tile)
  const int kkey = t >> 3;                 // slot within tile
  const int kdg  = (t & 7) ^ (kkey & 7);   // XOR'd d-block (bank spread)
  const int vd   = t & 63;                 // V: column d
  const int vkg  = t >> 6;                 // V: 8-key group

  float kr[8], vr[8]; float mbias = 0.f;

  auto LOADT = [&](int it) {   // gather tile it's live keys
    const int tb = it * KVB;
    const int krow = idx[tb + kkey];
    const float* kp = Kg + base + (size_t)krow * HD + 8*kdg;
    *(float4*)&kr[0] = *(const float4*)kp;
    *(float4*)&kr[4] = *(const float4*)(kp + 4);
    i32x4 ra = *(const i32x4*)&idx[tb + 8*vkg];
    i32x4 rb = *(const i32x4*)&idx[tb + 8*vkg + 4];
#pragma unroll
    for (int j = 0; j < 4; ++j) vr[j]   = Vg[base + (size_t)ra[j]*HD + vd];
#pragma unroll
    for (int j = 0; j < 4; ++j) vr[4+j] = Vg[base + (size_t)rb[j]*HD + vd];
    if (t < 64) mbias = bias[tb + t];
  };
  auto STORET = [&](int bf) {
    i32x4 kw;
    kw[0] = cvt_pk(kr[0], kr[1]); kw[1] = cvt_pk(kr[2], kr[3]);
    kw[2] = cvt_pk(kr[4], kr[5]); kw[3] = cvt_pk(kr[6], kr[7]);
    *(i32x4*)&Klds[bf][kkey*72 + 8*kdg] = kw;
    i32x4 vw;
    vw[0] = cvt_pk(vr[0], vr[1]); vw[1] = cvt_pk(vr[2], vr[3]);
    vw[2] = cvt_pk(vr[4], vr[5]); vw[3] = cvt_pk(vr[6], vr[7]);
    *(i32x4*)&Vtld[bf][vd*72 + 8*vkg] = vw;
    if (t < 64) MB[bf][t] = mbias;
  };

  f32x16 acc0 = {};  // O^T rows d=0..31
  f32x16 acc1 = {};  // O^T rows d=32..63
  float mrun = -1e30f;
  float lrun = 0.f;  // per-lane partial row-sum; merged across hi at epilogue
                     // (rescale factor is hi-uniform since tmax is shfl-merged)

  // One 32-key group (round-7 proven body). lastTile gates the bias add:
  // all-real tiles have bias == 0 exactly, so skipping the add is exact.
  auto GROUP = [&](int cur, int grp, bool lastTile) {
    const int kc = 32 * grp;
    // ---- S^T = K · Q^T  (rows = keys kc..kc+31, cols = q)
    f32x16 S = {};
    __builtin_amdgcn_s_setprio(1);
#pragma unroll
    for (int s = 0; s < 4; ++s) {
      bf16x8 kf = *(const bf16x8*)&Klds[cur][(kc + c)*72 + 16*s + 8*hi];
      S = __builtin_amdgcn_mfma_f32_32x32x16_bf16(kf, qf[s], S, 0, 0, 0);
    }
    __builtin_amdgcn_s_setprio(0);

    // sb[r]: logit2 for key kc + (r&3)+8*(r>>2)+4*hi, q=c
    float sb[16];
    if (lastTile) {
      f32x4 b4[4];
#pragma unroll
      for (int m = 0; m < 4; ++m)
        b4[m] = *(const f32x4*)&MB[cur][kc + 8*m + 4*hi];
#pragma unroll
      for (int r = 0; r < 16; ++r)
        sb[r] = S[r] + b4[r >> 2][r & 3];
    } else {
#pragma unroll
      for (int r = 0; r < 16; ++r) sb[r] = S[r];
    }

    // row max over this group's 32 keys
    float mx[8];
#pragma unroll
    for (int r = 0; r < 8; ++r) mx[r] = fmaxf(sb[r], sb[r+8]);
#pragma unroll
    for (int r = 0; r < 4; ++r) mx[r] = fmaxf(mx[r], mx[r+4]);
    float tmax = fmaxf(fmaxf(mx[0], mx[1]), fmaxf(mx[2], mx[3]));
    tmax = fmaxf(tmax, __shfl_xor(tmax, 32, 64));

    // defer-max: rescale only when the running max grows by > THR
    if (!__all(tmax <= mrun + THR)) {
      float mnew = fmaxf(mrun, tmax);
      float al = exp2v(mrun - mnew);
      acc0 *= al; acc1 *= al;
      lrun *= al; mrun = mnew;
    }

    // p = exp2(logit2 - m)
    float p0[8], p1[8];
#pragma unroll
    for (int r = 0; r < 8; ++r) p0[r] = exp2v(sb[r] - mrun);
#pragma unroll
    for (int r = 0; r < 8; ++r) p1[r] = exp2v(sb[8 + r] - mrun);

    // pack P to bf16 B-fragments (proven permlane recipe)
    int w0 = cvt_pk(p0[0], p0[1]), w1 = cvt_pk(p0[2], p0[3]);
    int w2 = cvt_pk(p0[4], p0[5]), w3 = cvt_pk(p0[6], p0[7]);
    swap32(w0, w2); swap32(w1, w3);
    i32x4 pq0 = {w0, w1, w2, w3};
    bf16x8 pb0 = __builtin_bit_cast(bf16x8, pq0);   // keys kc..kc+15
    int w4 = cvt_pk(p1[0], p1[1]), w5 = cvt_pk(p1[2], p1[3]);
    int w6 = cvt_pk(p1[4], p1[5]), w7 = cvt_pk(p1[6], p1[7]);
    swap32(w4, w6); swap32(w5, w7);
    i32x4 pq1 = {w4, w5, w6, w7};
    bf16x8 pb1 = __builtin_bit_cast(bf16x8, pq1);   // keys kc+16..kc+31

    // V fragments just-in-time (16 regs only)
    bf16x8 vA0 = *(const bf16x8*)&Vtld[cur][(c     )*72 + kc      + 8*hi];
    bf16x8 vA1 = *(const bf16x8*)&Vtld[cur][(c     )*72 + kc + 16 + 8*hi];
    bf16x8 vB0 = *(const bf16x8*)&Vtld[cur][(c + 32)*72 + kc      + 8*hi];
    bf16x8 vB1 = *(const bf16x8*)&Vtld[cur][(c + 32)*72 + kc + 16 + 8*hi];

    // ---- O^T += V^T · P^T
    __builtin_amdgcn_s_setprio(1);
    acc0 = __builtin_amdgcn_mfma_f32_32x32x16_bf16(vA0, pb0, acc0, 0, 0, 0);
    acc1 = __builtin_amdgcn_mfma_f32_32x32x16_bf16(vB0, pb0, acc1, 0, 0, 0);
    acc0 = __builtin_amdgcn_mfma_f32_32x32x16_bf16(vA1, pb1, acc0, 0, 0, 0);
    acc1 = __builtin_amdgcn_mfma_f32_32x32x16_bf16(vB1, pb1, acc1, 0, 0, 0);
    __builtin_amdgcn_s_setprio(0);

    // per-lane partial row-sum (no per-tile shfl)
    float s0 = ((p0[0]+p0[1]) + (p0[2]+p0[3])) + ((p0[4]+p0[5]) + (p0[6]+p0[7]));
    float s1 = ((p1[0]+p1[1]) + (p1[2]+p1[3])) + ((p1[4]+p1[5]) + (p1[6]+p1[7]));
    lrun += s0 + s1;
  };

  // ---- prologue
  LOADT(0); STORET(0);
  if (NTd > 1) LOADT(1);
  __syncthreads();

  for (int it = 0; it < NTd; ++it) {
    if (it + 1 < NTd) STORET((it + 1) & 1);
    if (it + 2 < NTd) LOADT(it + 2);
    const int cur = it & 1;
    const bool lt = (it == NTd - 1);
    GROUP(cur, 0, lt);
    GROUP(cur, 1, lt);
    __syncthreads();
  }

  // ---- epilogue: merge partial l across hi halves; normalize; store fp32
  float lfull = lrun + __shfl_xor(lrun, 32, 64);
  const float linv = 1.0f / lfull;
  float* op = Og + base + (size_t)(qbase + c) * HD + 4*hi;
#pragma unroll
  for (int m = 0; m < 4; ++m) {
    f32x4 o0, o1;
#pragma unroll
    for (int j = 0; j < 4; ++j) {
      o0[j] = acc0[4*m + j] * linv;
      o1[j] = acc1[4*m + j] * linv;
    }
    *(f32x4*)(op + 8*m)      = o0;   // d = 8m+4hi .. +3
    *(f32x4*)(op + 32 + 8*m) = o1;   // d = 32+8m+4hi .. +3
  }
}

extern "C" void kernel_launch(void* const* d_in, const int* in_sizes, int n_in,
                              void* d_out, int out_size, void* d_ws, size_t ws_size,
                              hipStream_t stream) {
    const float* Q = (const float*)d_in[0];
    const float* K = (const float*)d_in[1];
    const float* V = (const float*)d_in[2];
    const int*   M = (const int*)d_in[3];
    float* O = (float*)d_out;

    // ws layout: idx[4][2048] int | bias[4][2048] f32 | cnt[4] int
    char* ws = (char*)d_ws;
    int*   idxA  = (int*)ws;
    float* biasA = (float*)(ws + 4 * S_LEN * sizeof(int));
    int*   cntA  = (int*)(ws + 8 * S_LEN * sizeof(int));

    hipLaunchKernelGGL(build_idx, dim3(1), dim3(256), 0, stream, M, idxA, biasA, cntA);
    hipLaunchKernelGGL(attn_fwd, dim3(512), dim3(512), 0, stream,
                       Q, K, V, idxA, biasA, cntA, O);
}